// Round 2
// 994.667 us; speedup vs baseline: 1.3103x; 1.3103x over previous
//
#include <hip/hip_runtime.h>

#define T_TOK 16384
#define NCODE 8192
#define DIM   256
#define BN    64
#define ITERS (NCODE / BN)   // 128
#define WG_TOKS 64

typedef __attribute__((ext_vector_type(8))) short short8;
typedef __attribute__((ext_vector_type(4))) float floatx4;

__device__ __forceinline__ short f2bf(float x) {
  union { float f; unsigned u; } a; a.f = x;
  unsigned r = a.u + 0x7fffu + ((a.u >> 16) & 1u);   // RNE, no NaN inputs here
  return (short)(r >> 16);
}

// Prep: codebook fp32 -> bf16 copy + per-code squared norms.
// grid 2048 x 256 threads: one wave per code row (256 dims / 64 lanes = float4 each)
__global__ void vq_prep(const float* __restrict__ C, short* __restrict__ cbf,
                        float* __restrict__ cn) {
  int k = blockIdx.x * 4 + (threadIdx.x >> 6);
  int lane = threadIdx.x & 63;
  float4 v = *(const float4*)(C + k * DIM + lane * 4);
  short4 o;
  o.x = f2bf(v.x); o.y = f2bf(v.y); o.z = f2bf(v.z); o.w = f2bf(v.w);
  *(short4*)(cbf + k * DIM + lane * 4) = o;
  float d = v.x * v.x + v.y * v.y + v.z * v.z + v.w * v.w;
  #pragma unroll
  for (int s = 1; s < 64; s <<= 1) d += __shfl_xor(d, s);
  if (lane == 0) cn[k] = d;
}

// Transposed bf16 codebook cbT[dim][code] so the PV B-operand is a contiguous
// short8 load. Tiled 64x64 transpose through LDS, reading the bf16 cbf.
// grid 512 x 256 threads.
__global__ void vq_transpose(const short* __restrict__ cbf, short* __restrict__ cbT) {
  __shared__ short ts[64][72];
  const int t = threadIdx.x;
  const int k0 = (blockIdx.x >> 2) * 64;   // code tile
  const int d0 = (blockIdx.x & 3) * 64;    // dim tile
  const int row = t >> 2, c16 = (t & 3) * 16;
  const short* src = cbf + (size_t)(k0 + row) * DIM + d0 + c16;
  *(short8*)&ts[row][c16]     = *(const short8*)src;
  *(short8*)&ts[row][c16 + 8] = *(const short8*)(src + 8);
  __syncthreads();
  short8 o0, o1;
  #pragma unroll
  for (int j = 0; j < 8; ++j) { o0[j] = ts[c16 + j][row]; o1[j] = ts[c16 + 8 + j][row]; }
  short* dst = cbT + (size_t)(d0 + row) * NCODE + k0 + c16;
  *(short8*)dst = o0;
  *(short8*)(dst + 8) = o1;
}

// Fused flash-style VQ, v2: 512 threads (8 waves, 2/SIMD), one-chunk-ahead
// software pipeline. Codebook B-fragments come straight from L2 into registers
// (4 MB bf16 codebook is L2-resident; intra-WG reuse is only 2x, staging buys
// nothing); u_noise is coalesced float4 -> double-buffered LDS, prefetched a
// full iteration early. 2 barriers/iter (was 3).
// S-phase: wave = 32 tokens x 16 codes.  PV-phase: wave = 64 tokens x 32 dims.
__global__ __launch_bounds__(512, 2) void vq_main(
    const float* __restrict__ z, const float* __restrict__ u_noise,
    const short* __restrict__ cbf, const short* __restrict__ cbT,
    const float* __restrict__ cn, float* __restrict__ out)
{
  __shared__ float ubuf[2][64][68];    // u chunk, double-buffered   34816 B
  __shared__ short pbuf[64][72];       // P chunk [token][code]       9216 B
  __shared__ float lred[4][WG_TOKS];
  __shared__ float lbuf[WG_TOKS];
  __shared__ float lossred[8];

  const int tid  = threadIdx.x;
  const int wid  = tid >> 6;
  const int lane = tid & 63;
  const int q    = lane >> 4;
  const int cl   = lane & 15;
  const int tokBase  = blockIdx.x * WG_TOKS;
  const int sTokHalf = (wid >> 2) * 32;  // S-phase: which 32 tokens
  const int sCodeQ   = (wid & 3) * 16;   // S-phase: which 16 codes of the chunk
  const int pvDim    = wid * 32;         // PV-phase: which 32 dims
  const int urow = tid >> 3;             // u staging: token row
  const int ucol = (tid & 7) * 8;        // u staging: code col (8 floats/thread)

  // z A-fragments, bf16, resident in registers: 2 Mtiles x 8 ksteps
  short8 za[2][8];
  #pragma unroll
  for (int mt = 0; mt < 2; ++mt) {
    const float* zp = z + (size_t)(tokBase + sTokHalf + mt * 16 + cl) * DIM + q * 8;
    #pragma unroll
    for (int ks = 0; ks < 8; ++ks) {
      float4 f0 = *(const float4*)(zp + ks * 32);
      float4 f1 = *(const float4*)(zp + ks * 32 + 4);
      short8 t;
      t[0] = f2bf(f0.x); t[1] = f2bf(f0.y); t[2] = f2bf(f0.z); t[3] = f2bf(f0.w);
      t[4] = f2bf(f1.x); t[5] = f2bf(f1.y); t[6] = f2bf(f1.z); t[7] = f2bf(f1.w);
      za[mt][ks] = t;
    }
  }

  // O accumulator: 64 tokens x 32 dims per wave (4x2 tiles of 16x16)
  floatx4 Oa[4][2];
  #pragma unroll
  for (int a = 0; a < 4; ++a)
    #pragma unroll
    for (int b = 0; b < 2; ++b)
      Oa[a][b] = (floatx4){0.f, 0.f, 0.f, 0.f};
  float lpart[2][4] = {{0.f, 0.f, 0.f, 0.f}, {0.f, 0.f, 0.f, 0.f}};

  // one-chunk-ahead register pipeline state
  short8 sb[2][8];   // S-phase B-fragments (16 codes x 256 dims / wave)
  short8 vb[2][4];   // PV-phase B-fragments (32 dims x 64 codes / wave)
  float  nkc[2];

  // ---- prologue: chunk 0 into pipeline ----
  {
    const short* sp = cbf + (size_t)(sCodeQ + cl) * DIM + q * 8;
    #pragma unroll
    for (int ks = 0; ks < 8; ++ks) sb[0][ks] = *(const short8*)(sp + ks * 32);
    #pragma unroll
    for (int nt = 0; nt < 2; ++nt) {
      const short* vp = cbT + (size_t)(pvDim + nt * 16 + cl) * NCODE + q * 8;
      vb[0][nt * 2 + 0] = *(const short8*)vp;
      vb[0][nt * 2 + 1] = *(const short8*)(vp + 32);
    }
    nkc[0] = cn[sCodeQ + cl];
    const float* up = u_noise + (size_t)(tokBase + urow) * NCODE + ucol;
    float4 u0 = *(const float4*)up;
    float4 u1 = *(const float4*)(up + 4);
    *(float4*)&ubuf[0][urow][ucol] = u0;
    *(float4*)&ubuf[0][urow][ucol + 4] = u1;
  }
  __syncthreads();

// Body for one K-chunk; PB is a literal (0/1) so all pipeline-buffer indices
// are compile-time constants (no scratch).
#define VQ_BODY(PB, IT)                                                        \
  {                                                                            \
    const int kbn = (((IT) + 1) & (ITERS - 1)) * BN;                           \
    /* issue u prefetch for next chunk (HBM; lands in regs, written late) */   \
    const float* upn = u_noise + (size_t)(tokBase + urow) * NCODE + kbn + ucol;\
    float4 un0 = *(const float4*)upn;                                          \
    float4 un1 = *(const float4*)(upn + 4);                                    \
    /* S phase: 32 tok x 16 codes, K=256, from prefetched regs */              \
    floatx4 acc[2];                                                            \
    acc[0] = (floatx4){0.f, 0.f, 0.f, 0.f};                                    \
    acc[1] = (floatx4){0.f, 0.f, 0.f, 0.f};                                    \
    _Pragma("unroll")                                                          \
    for (int ks = 0; ks < 8; ++ks) {                                           \
      acc[0] = __builtin_amdgcn_mfma_f32_16x16x32_bf16(za[0][ks], sb[PB][ks],  \
                                                       acc[0], 0, 0, 0);       \
      acc[1] = __builtin_amdgcn_mfma_f32_16x16x32_bf16(za[1][ks], sb[PB][ks],  \
                                                       acc[1], 0, 0, 0);       \
    }                                                                          \
    /* prefetch next S-B fragments + code norms (L2-resident) */               \
    {                                                                          \
      const short* sp = cbf + (size_t)(kbn + sCodeQ + cl) * DIM + q * 8;       \
      _Pragma("unroll")                                                        \
      for (int ks = 0; ks < 8; ++ks)                                           \
        sb[1 - PB][ks] = *(const short8*)(sp + ks * 32);                       \
      nkc[1 - PB] = cn[kbn + sCodeQ + cl];                                     \
    }                                                                          \
    /* epilogue: p = exp(2 z.c - ||c||^2) / (-log u) */                        \
    {                                                                          \
      const float nk = nkc[PB];                                                \
      _Pragma("unroll")                                                        \
      for (int mt = 0; mt < 2; ++mt)                                           \
        _Pragma("unroll")                                                      \
        for (int r = 0; r < 4; ++r) {                                          \
          const int tokL = sTokHalf + mt * 16 + q * 4 + r;                     \
          float uvv = ubuf[PB][tokL][sCodeQ + cl];                             \
          float nl = -__logf(uvv);                                             \
          float p = __expf(2.f * acc[mt][r] - nk) *                            \
                    __builtin_amdgcn_rcpf(nl);                                 \
          lpart[mt][r] += p;                                                   \
          pbuf[tokL][sCodeQ + cl] = f2bf(p);                                   \
        }                                                                      \
    }                                                                          \
    __syncthreads();                                                           \
    /* PV phase: O(64 tok x 32 dims) += P(64x64) @ C(64 x dims) */             \
    _Pragma("unroll")                                                          \
    for (int ks = 0; ks < 2; ++ks) {                                           \
      short8 pa[4];                                                            \
      _Pragma("unroll")                                                        \
      for (int mt = 0; mt < 4; ++mt)                                           \
        pa[mt] = *(const short8*)&pbuf[mt * 16 + cl][ks * 32 + q * 8];         \
      _Pragma("unroll")                                                        \
      for (int nt = 0; nt < 2; ++nt)                                           \
        _Pragma("unroll")                                                      \
        for (int mt = 0; mt < 4; ++mt)                                         \
          Oa[mt][nt] = __builtin_amdgcn_mfma_f32_16x16x32_bf16(                \
              pa[mt], vb[PB][nt * 2 + ks], Oa[mt][nt], 0, 0, 0);               \
    }                                                                          \
    /* prefetch next PV-B fragments (L2-resident) */                           \
    _Pragma("unroll")                                                          \
    for (int nt = 0; nt < 2; ++nt) {                                           \
      const short* vp =                                                        \
          cbT + (size_t)(pvDim + nt * 16 + cl) * NCODE + kbn + q * 8;          \
      vb[1 - PB][nt * 2 + 0] = *(const short8*)vp;                             \
      vb[1 - PB][nt * 2 + 1] = *(const short8*)(vp + 32);                      \
    }                                                                          \
    /* write-late: u for next chunk into the other LDS buffer */               \
    *(float4*)&ubuf[1 - PB][urow][ucol] = un0;                                 \
    *(float4*)&ubuf[1 - PB][urow][ucol + 4] = un1;                             \
    __syncthreads();                                                           \
  }

  #pragma unroll 1
  for (int it = 0; it < ITERS; it += 2) {
    VQ_BODY(0, it)
    VQ_BODY(1, it + 1)
  }
#undef VQ_BODY

  // ---- reduce l: over 16 col-lanes, then over the 4 code-quarter waves ----
  #pragma unroll
  for (int mt = 0; mt < 2; ++mt)
    #pragma unroll
    for (int r = 0; r < 4; ++r) {
      float v = lpart[mt][r];
      v += __shfl_xor(v, 1); v += __shfl_xor(v, 2);
      v += __shfl_xor(v, 4); v += __shfl_xor(v, 8);
      if (cl == 0) lred[wid & 3][sTokHalf + mt * 16 + q * 4 + r] = v;
    }
  __syncthreads();
  if (tid < WG_TOKS)
    lbuf[tid] = (lred[0][tid] + lred[1][tid]) + (lred[2][tid] + lred[3][tid]);
  __syncthreads();

  // ---- normalize, store z_q, accumulate commit loss ----
  float lossAcc = 0.f;
  #pragma unroll
  for (int mt = 0; mt < 4; ++mt)
    #pragma unroll
    for (int nt = 0; nt < 2; ++nt)
      #pragma unroll
      for (int r = 0; r < 4; ++r) {
        const int tokL = mt * 16 + q * 4 + r;
        const int dimG = pvDim + nt * 16 + cl;
        float val = Oa[mt][nt][r] / lbuf[tokL];
        const size_t off = (size_t)(tokBase + tokL) * DIM + dimG;
        out[off] = val;
        float dd = val - z[off];
        lossAcc += dd * dd;
      }
  #pragma unroll
  for (int s = 32; s > 0; s >>= 1) lossAcc += __shfl_xor(lossAcc, s);
  if (lane == 0) lossred[wid] = lossAcc;
  __syncthreads();
  if (tid == 0) {
    float t8 = 0.f;
    #pragma unroll
    for (int w = 0; w < 8; ++w) t8 += lossred[w];
    atomicAdd(out + (size_t)T_TOK * DIM, t8 * (2.f / (float)(T_TOK * DIM)));
  }
}

extern "C" void kernel_launch(void* const* d_in, const int* in_sizes, int n_in,
                              void* d_out, int out_size, void* d_ws, size_t ws_size,
                              hipStream_t stream) {
  const float* z = (const float*)d_in[0];       // [4,4096,256] fp32
  const float* C = (const float*)d_in[1];       // [8192,256]   fp32
  const float* u = (const float*)d_in[2];       // [16384,8192] fp32
  float* out = (float*)d_out;                   // [16384*256] z_q + [1] loss
  short* cbf = (short*)d_ws;                                      // 4 MB bf16 codebook
  float* cn  = (float*)((char*)d_ws + (size_t)NCODE * DIM * 2);   // 32 KB norms
  short* cbT = (short*)((char*)d_ws + (size_t)NCODE * DIM * 2 + (size_t)NCODE * 4); // 4 MB transposed

  hipMemsetAsync(out + (size_t)T_TOK * DIM, 0, sizeof(float), stream);
  vq_prep<<<NCODE / 4, 256, 0, stream>>>(C, cbf, cn);
  vq_transpose<<<(NCODE / 64) * (DIM / 64), 256, 0, stream>>>(cbf, cbT);
  vq_main<<<T_TOK / WG_TOKS, 512, 0, stream>>>(z, u, cbf, cbT, cn, out);
}